// Round 10
// baseline (362.686 us; speedup 1.0000x reference)
//
#include <hip/hip_runtime.h>

// ---------------------------------------------------------------------------
// Compile-time Cayley table for Cl(4,0), blades in short-lex order.
// For each (i,k): exactly one output blade j = idx(ba ^ bb), sign from
// merge-swap parity (metric all +1). constexpr => folded after unrolling.
// ---------------------------------------------------------------------------
struct Tables {
    signed char  sgn[16][16];
    unsigned char out[16][16];
};

constexpr int pc4(int x) {
    return ((x >> 0) & 1) + ((x >> 1) & 1) + ((x >> 2) & 1) + ((x >> 3) & 1);
}

constexpr Tables make_tables() {
    Tables t{};
    int bitmaps[16] = {};
    int n = 0;
    for (int g = 0; g <= 4; ++g)
        for (int bm = 0; bm < 16; ++bm)
            if (pc4(bm) == g) bitmaps[n++] = bm;
    int inv[16] = {};
    for (int i = 0; i < 16; ++i) inv[bitmaps[i]] = i;
    for (int i = 0; i < 16; ++i) {
        for (int k = 0; k < 16; ++k) {
            const int ba = bitmaps[i];
            const int bb = bitmaps[k];
            int swaps = 0;
            for (int sh = ba >> 1; sh; sh >>= 1) swaps += pc4(sh & bb);
            t.sgn[i][k] = (swaps & 1) ? -1 : 1;
            t.out[i][k] = (unsigned char)inv[ba ^ bb];
        }
    }
    return t;
}

constexpr Tables TBL = make_tables();

typedef float f32x4 __attribute__((ext_vector_type(4)));

// ROW = 20 floats (80 B): 16B-aligned rows => all LDS ops are b128;
// start bank 20*t mod 32 spreads over 8 banksets => <=4-way conflicts.
// LDS/block = 2*256*20*4 = 40960 B => 4 blocks/CU.
#define ROW 20

__global__ __launch_bounds__(256) void clifford_gp_kernel(
        const float4* __restrict__ a4,
        const float4* __restrict__ b4,
        float4* __restrict__ o4,
        int n_mv) {
    __shared__ __align__(16) float lds_a[256 * ROW];
    __shared__ __align__(16) float lds_b[256 * ROW];

    const int t = threadIdx.x;
    const long long base4 = (long long)blockIdx.x * 1024;  // tile base (float4 units)
    const long long n4 = (long long)n_mv * 4;
    const bool full = (base4 + 1024) <= n4;   // uniform: whole tile in range

    // ---- phase 1: issue ALL 8 global loads before ANY LDS write (MLP = 8).
    float4 va[4], vb[4];
    if (full) {
        #pragma unroll
        for (int r = 0; r < 4; ++r) va[r] = a4[base4 + r * 256 + t];
        #pragma unroll
        for (int r = 0; r < 4; ++r) vb[r] = b4[base4 + r * 256 + t];
    } else {
        #pragma unroll
        for (int r = 0; r < 4; ++r) {
            const long long g = base4 + r * 256 + t;
            va[r] = (g < n4) ? a4[g] : make_float4(0.f, 0.f, 0.f, 0.f);
            vb[r] = (g < n4) ? b4[g] : make_float4(0.f, 0.f, 0.f, 0.f);
        }
    }

    // ---- phase 2: scatter into padded LDS rows (b128 stores, 16B-aligned)
    #pragma unroll
    for (int r = 0; r < 4; ++r) {
        const int idx = r * 256 + t;
        const int mv = idx >> 2;
        const int q  = idx & 3;
        *reinterpret_cast<float4*>(&lds_a[mv * ROW + q * 4]) = va[r];
        *reinterpret_cast<float4*>(&lds_b[mv * ROW + q * 4]) = vb[r];
    }
    __syncthreads();

    // ---- phase 3: own row -> registers (b128 reads), 256 signed FMAs
    float av[16], bv[16], ov[16];
    #pragma unroll
    for (int j = 0; j < 4; ++j) {
        const float4 ta = *reinterpret_cast<const float4*>(&lds_a[t * ROW + j * 4]);
        av[j * 4 + 0] = ta.x; av[j * 4 + 1] = ta.y;
        av[j * 4 + 2] = ta.z; av[j * 4 + 3] = ta.w;
        const float4 tb = *reinterpret_cast<const float4*>(&lds_b[t * ROW + j * 4]);
        bv[j * 4 + 0] = tb.x; bv[j * 4 + 1] = tb.y;
        bv[j * 4 + 2] = tb.z; bv[j * 4 + 3] = tb.w;
    }

    #pragma unroll
    for (int j = 0; j < 16; ++j) ov[j] = 0.0f;

    #pragma unroll
    for (int i = 0; i < 16; ++i) {
        #pragma unroll
        for (int k = 0; k < 16; ++k) {
            const int j = TBL.out[i][k];       // compile-time constant
            if (TBL.sgn[i][k] > 0) {
                ov[j] = fmaf(av[i], bv[k], ov[j]);
            } else {
                ov[j] = fmaf(-av[i], bv[k], ov[j]);
            }
        }
    }

    // ---- phase 4: result row back to LDS; barrier; coalesced gather-out
    //      (plain caching stores — nt stores measured 10% WORSE in R6)
    #pragma unroll
    for (int j = 0; j < 4; ++j) {
        *reinterpret_cast<float4*>(&lds_a[t * ROW + j * 4]) =
            make_float4(ov[j * 4 + 0], ov[j * 4 + 1], ov[j * 4 + 2], ov[j * 4 + 3]);
    }
    __syncthreads();

    if (full) {
        #pragma unroll
        for (int r = 0; r < 4; ++r) {
            const int idx = r * 256 + t;
            const int mv = idx >> 2;
            const int q  = idx & 3;
            o4[base4 + idx] =
                *reinterpret_cast<const float4*>(&lds_a[mv * ROW + q * 4]);
        }
    } else {
        #pragma unroll
        for (int r = 0; r < 4; ++r) {
            const int idx = r * 256 + t;
            if (base4 + idx < n4) {
                const int mv = idx >> 2;
                const int q  = idx & 3;
                o4[base4 + idx] =
                    *reinterpret_cast<const float4*>(&lds_a[mv * ROW + q * 4]);
            }
        }
    }
}

// ---------------------------------------------------------------------------
// CALIBRATION dispatch (this round only): canonical streaming copy, the m13
// pattern — coalesced f32x4, MLP=8, no LDS, no barriers. Copies `a` into
// d_ws. Its rocprof row measures the environment's achievable HBM BW with a
// known-good kernel (rule #10: external baseline before declaring a ceiling).
// ---------------------------------------------------------------------------
__global__ __launch_bounds__(256) void calib_copy(
        const f32x4* __restrict__ src,
        f32x4* __restrict__ dst,
        long long seg) {          // segment length in f32x4; 8 segments total
    const long long g = (long long)blockIdx.x * 256 + threadIdx.x;
    if (g < seg) {
        f32x4 v[8];
        #pragma unroll
        for (int s = 0; s < 8; ++s) v[s] = src[g + s * seg];
        #pragma unroll
        for (int s = 0; s < 8; ++s) dst[g + s * seg] = v[s];
    }
}

extern "C" void kernel_launch(void* const* d_in, const int* in_sizes, int n_in,
                              void* d_out, int out_size, void* d_ws, size_t ws_size,
                              hipStream_t stream) {
    const float4* a4 = (const float4*)d_in[0];
    const float4* b4 = (const float4*)d_in[1];
    // d_in[2] (cayley) intentionally unused: table folded at compile time.
    float4* o4 = (float4*)d_out;

    const int n_mv = in_sizes[0] / 16;            // 2048*1024 = 2,097,152
    const int block = 256;
    const int grid = (n_mv + block - 1) / block;  // 8192 blocks

    clifford_gp_kernel<<<grid, block, 0, stream>>>(a4, b4, o4, n_mv);

    // Calibration copy: a (up to 128 MB, limited by ws capacity) -> d_ws.
    const long long n4_total = (long long)in_sizes[0] / 4;            // f32x4 count
    const long long n4_fit   = (long long)(ws_size / 16);
    const long long n4w      = (n4_total < n4_fit) ? n4_total : n4_fit;
    const long long seg      = n4w >> 3;
    if (seg > 0) {
        const int cgrid = (int)((seg + 255) / 256);
        calib_copy<<<cgrid, 256, 0, stream>>>(
            (const f32x4*)d_in[0], (f32x4*)d_ws, seg);
    }
}